// Round 1
// baseline (572.820 us; speedup 1.0000x reference)
//
#include <hip/hip_runtime.h>

#define HRANGE 8192
#define DIM 64
#define RANK 16

// One thread per (b, d): v = end_core[h3][d]; v = v @ cores[0][h1][d]; v = v @ cores[1][h2][d];
// out[b][d] = dot(start_core[h0][d], v).  All fp32, float4 loads throughout.
__global__ __launch_bounds__(256) void tt_embed_kernel(
    const int* __restrict__ hs,           // (B, 4) int32
    const float* __restrict__ start_core, // (HRANGE, DIM, RANK)
    const float* __restrict__ end_core,   // (HRANGE, DIM, RANK)
    const float* __restrict__ cores,      // (2, HRANGE, DIM, RANK, RANK)
    float* __restrict__ out,              // (B, DIM)
    int B)
{
    const int tid = blockIdx.x * blockDim.x + threadIdx.x;
    const int b = tid >> 6;   // wave-uniform
    const int d = tid & 63;
    if (b >= B) return;

    const int h0 = hs[b * 4 + 0];
    const int h1 = hs[b * 4 + 1];
    const int h2 = hs[b * 4 + 2];
    const int h3 = hs[b * 4 + 3];

    // v = end_core[h3][d][:]
    float v[RANK];
    {
        const float4* e = reinterpret_cast<const float4*>(
            end_core + (((size_t)h3 * DIM) + d) * RANK);
        #pragma unroll
        for (int j = 0; j < 4; ++j) {
            float4 t = e[j];
            v[4 * j + 0] = t.x; v[4 * j + 1] = t.y;
            v[4 * j + 2] = t.z; v[4 * j + 3] = t.w;
        }
    }

    // v = einsum('rs,r->s', cores[c][h][d], v) for c = 0, 1
    #pragma unroll
    for (int c = 0; c < 2; ++c) {
        const int h = (c == 0) ? h1 : h2;
        const float4* M = reinterpret_cast<const float4*>(
            cores + ((((size_t)c * HRANGE + h) * DIM) + d) * (RANK * RANK));
        float w[RANK];
        #pragma unroll
        for (int s = 0; s < RANK; ++s) w[s] = 0.f;
        #pragma unroll
        for (int r = 0; r < RANK; ++r) {
            const float vr = v[r];
            #pragma unroll
            for (int j = 0; j < 4; ++j) {
                float4 m = M[r * 4 + j];
                w[4 * j + 0] = fmaf(vr, m.x, w[4 * j + 0]);
                w[4 * j + 1] = fmaf(vr, m.y, w[4 * j + 1]);
                w[4 * j + 2] = fmaf(vr, m.z, w[4 * j + 2]);
                w[4 * j + 3] = fmaf(vr, m.w, w[4 * j + 3]);
            }
        }
        #pragma unroll
        for (int s = 0; s < RANK; ++s) v[s] = w[s];
    }

    // out[b][d] = dot(start_core[h0][d], v)
    float acc = 0.f;
    {
        const float4* sc = reinterpret_cast<const float4*>(
            start_core + (((size_t)h0 * DIM) + d) * RANK);
        #pragma unroll
        for (int j = 0; j < 4; ++j) {
            float4 t = sc[j];
            acc = fmaf(t.x, v[4 * j + 0], acc);
            acc = fmaf(t.y, v[4 * j + 1], acc);
            acc = fmaf(t.z, v[4 * j + 2], acc);
            acc = fmaf(t.w, v[4 * j + 3], acc);
        }
    }
    out[(size_t)b * DIM + d] = acc;
}

extern "C" void kernel_launch(void* const* d_in, const int* in_sizes, int n_in,
                              void* d_out, int out_size, void* d_ws, size_t ws_size,
                              hipStream_t stream) {
    const int*   hs         = (const int*)d_in[0];
    const float* start_core = (const float*)d_in[1];
    const float* end_core   = (const float*)d_in[2];
    const float* cores      = (const float*)d_in[3];
    float*       out        = (float*)d_out;

    const int B = in_sizes[0] / 4;           // 16384
    const int total = B * DIM;               // one thread per (b, d)
    dim3 block(256);
    dim3 grid((total + 255) / 256);
    tt_embed_kernel<<<grid, block, 0, stream>>>(hs, start_core, end_core, cores, out, B);
}

// Round 2
// 330.024 us; speedup vs baseline: 1.7357x; 1.7357x over previous
//
#include <hip/hip_runtime.h>

#define HRANGE 8192
#define DIM 64
#define RANK 16
#define WPB 2                  // b's (waves) per block
#define BLOCK (WPB * 64)

// One wave per batch element b; lane = d.
// Core rows are staged through LDS in 8KB chunks (2 M-rows for all 64 d):
//  - global: segment-gather, 8 lanes per 128B segment -> 8 lines/instr (coalesced-equivalent)
//  - LDS: XOR swizzle ((d&7)<<2 on float index) -> uniform 8 words/bank on both
//    ds_write_b128 and ds_read_b128 (minimal for b128 wave ops).
__global__ __launch_bounds__(BLOCK) void tt_embed_kernel(
    const int* __restrict__ hs,           // (B, 4) int32
    const float* __restrict__ start_core, // (HRANGE, DIM, RANK)
    const float* __restrict__ end_core,   // (HRANGE, DIM, RANK)
    const float* __restrict__ cores,      // (2, HRANGE, DIM, RANK, RANK)
    float* __restrict__ out,              // (B, DIM)
    int B)
{
    __shared__ float lds[WPB][2048];      // 8 KB per wave
    const int wave = threadIdx.x >> 6;
    const int lane = threadIdx.x & 63;
    int b = blockIdx.x * WPB + wave;
    if (b >= B) b = B - 1;                // duplicate work, same value written
    const int d = lane;
    const int a = lane >> 3;              // segment index (d-group) 0..7
    const int cslot = lane & 7;           // 16B slot within 128B segment

    const int h0 = hs[b * 4 + 0];
    const int h1 = hs[b * 4 + 1];
    const int h2 = hs[b * 4 + 2];
    const int h3 = hs[b * 4 + 3];

    // v = end_core[h3][d][:]   (4 KB/b -> direct gather, minor traffic)
    float v[RANK];
    {
        const float4* e = reinterpret_cast<const float4*>(
            end_core + (((size_t)h3 * DIM) + d) * RANK);
        #pragma unroll
        for (int j = 0; j < 4; ++j) {
            float4 t = e[j];
            v[4 * j + 0] = t.x; v[4 * j + 1] = t.y;
            v[4 * j + 2] = t.z; v[4 * j + 3] = t.w;
        }
    }

    float* myLds = lds[wave];

    #pragma unroll
    for (int cc = 0; cc < 2; ++cc) {
        const int h = cc ? h2 : h1;
        const float* __restrict__ row =
            cores + (((size_t)cc * HRANGE + h) * DIM) * (RANK * RANK);
        float w[RANK];
        #pragma unroll
        for (int s = 0; s < RANK; ++s) w[s] = 0.f;

        #pragma unroll
        for (int k = 0; k < 8; ++k) {     // M-rows r = 2k, 2k+1
            // stage 8KB: for each d, floats [k*32, k*32+32)
            #pragma unroll
            for (int m = 0; m < 8; ++m) {
                const int dd = 8 * m + a;
                float4 t = *reinterpret_cast<const float4*>(
                    row + (size_t)dd * (RANK * RANK) + k * 2 * RANK + cslot * 4);
                // linear float slot = m*256 + lane*4  (== dd*32 + cslot*4)
                const int slot = (m * 256 + lane * 4) ^ (a << 2);
                *reinterpret_cast<float4*>(myLds + slot) = t;
            }
            __syncthreads();
            // consume rows r = 2k, 2k+1 for own d
            #pragma unroll
            for (int rp = 0; rp < 2; ++rp) {
                const float vr = v[2 * k + rp];
                #pragma unroll
                for (int j = 0; j < 4; ++j) {
                    const int slot = (d * 32 + rp * 16 + j * 4) ^ ((d & 7) << 2);
                    float4 mv = *reinterpret_cast<const float4*>(myLds + slot);
                    w[4 * j + 0] = fmaf(vr, mv.x, w[4 * j + 0]);
                    w[4 * j + 1] = fmaf(vr, mv.y, w[4 * j + 1]);
                    w[4 * j + 2] = fmaf(vr, mv.z, w[4 * j + 2]);
                    w[4 * j + 3] = fmaf(vr, mv.w, w[4 * j + 3]);
                }
            }
            __syncthreads();              // WAR: next chunk overwrites
        }
        #pragma unroll
        for (int s = 0; s < RANK; ++s) v[s] = w[s];
    }

    // out[b][d] = dot(start_core[h0][d], v)
    float acc = 0.f;
    {
        const float4* sc = reinterpret_cast<const float4*>(
            start_core + (((size_t)h0 * DIM) + d) * RANK);
        #pragma unroll
        for (int j = 0; j < 4; ++j) {
            float4 t = sc[j];
            acc = fmaf(t.x, v[4 * j + 0], acc);
            acc = fmaf(t.y, v[4 * j + 1], acc);
            acc = fmaf(t.z, v[4 * j + 2], acc);
            acc = fmaf(t.w, v[4 * j + 3], acc);
        }
    }
    out[(size_t)b * DIM + d] = acc;
}

extern "C" void kernel_launch(void* const* d_in, const int* in_sizes, int n_in,
                              void* d_out, int out_size, void* d_ws, size_t ws_size,
                              hipStream_t stream) {
    const int*   hs         = (const int*)d_in[0];
    const float* start_core = (const float*)d_in[1];
    const float* end_core   = (const float*)d_in[2];
    const float* cores      = (const float*)d_in[3];
    float*       out        = (float*)d_out;

    const int B = in_sizes[0] / 4;        // 16384
    dim3 block(BLOCK);
    dim3 grid((B + WPB - 1) / WPB);
    tt_embed_kernel<<<grid, block, 0, stream>>>(hs, start_core, end_core, cores, out, B);
}

// Round 3
// 261.315 us; speedup vs baseline: 2.1921x; 1.2629x over previous
//
#include <hip/hip_runtime.h>

#define HRANGE 8192
#define DIM 64
#define RANK 16

// ---------------------------------------------------------------------------
// Plan: counting-sort b's by h1 (for stage-1) and h2 (for stage-2), then one
// block per h-bin loads its 64KB core row into REGISTERS once and applies it
// to all b's in the bin. Cuts core traffic from demand (2x1GB) to unique
// (~2x443MB). end_core/start_core (32MB each) are gathered directly (L3-hot).
// ---------------------------------------------------------------------------

__device__ __forceinline__ void fma4(float4& a, float s, const float4& m) {
    a.x = fmaf(s, m.x, a.x); a.y = fmaf(s, m.y, a.y);
    a.z = fmaf(s, m.z, a.z); a.w = fmaf(s, m.w, a.w);
}

__global__ __launch_bounds__(256) void zero_hist(int* hist) {
    int i = blockIdx.x * blockDim.x + threadIdx.x;
    if (i < 2 * HRANGE) hist[i] = 0;
}

__global__ __launch_bounds__(256) void hist_kernel(const int* __restrict__ hs,
                                                   int* hist1, int* hist2, int B) {
    int b = blockIdx.x * blockDim.x + threadIdx.x;
    if (b >= B) return;
    atomicAdd(&hist1[hs[b * 4 + 1]], 1);
    atomicAdd(&hist2[hs[b * 4 + 2]], 1);
}

// single-block exclusive scan of two 8192-bin histograms
__global__ __launch_bounds__(1024) void scan_kernel(const int* __restrict__ hist1,
                                                    const int* __restrict__ hist2,
                                                    int* off1, int* cur1,
                                                    int* off2, int* cur2) {
    __shared__ int part[1024];
    const int t = threadIdx.x;
    for (int which = 0; which < 2; ++which) {
        const int* hist = which ? hist2 : hist1;
        int* off = which ? off2 : off1;
        int* cur = which ? cur2 : cur1;
        int loc[8]; int sum = 0;
        #pragma unroll
        for (int i = 0; i < 8; ++i) { loc[i] = sum; sum += hist[t * 8 + i]; }
        part[t] = sum;
        __syncthreads();
        for (int dstep = 1; dstep < 1024; dstep <<= 1) {
            int v_ = (t >= dstep) ? part[t - dstep] : 0;
            __syncthreads();
            part[t] += v_;
            __syncthreads();
        }
        int base = (t == 0) ? 0 : part[t - 1];
        #pragma unroll
        for (int i = 0; i < 8; ++i) { int o = base + loc[i]; off[t*8+i] = o; cur[t*8+i] = o; }
        __syncthreads();
    }
}

__global__ __launch_bounds__(256) void scatter_kernel(const int* __restrict__ hs,
                                                      int* cur1, int* cur2,
                                                      int* list1, int* list2, int B) {
    int b = blockIdx.x * blockDim.x + threadIdx.x;
    if (b >= B) return;
    int p1 = atomicAdd(&cur1[hs[b * 4 + 1]], 1); list1[p1] = b;
    int p2 = atomicAdd(&cur2[hs[b * 4 + 2]], 1); list2[p2] = b;
}

// pass1: v1[b] = einsum('drs,dr->ds', cores[0][h1[b]], end_core[h3[b]])
// one block per h; thread t -> (d = t>>2, s-quad q = t&3); core row in regs.
__global__ __launch_bounds__(256) void pass1_kernel(const int* __restrict__ hs,
                                                    const float* __restrict__ end_core,
                                                    const float* __restrict__ cores0,
                                                    const int* __restrict__ off1,
                                                    const int* __restrict__ hist1,
                                                    const int* __restrict__ list1,
                                                    float* __restrict__ v1) {
    const int h = blockIdx.x;
    const int cnt = hist1[h];
    if (cnt == 0) return;
    const int beg = off1[h];
    const int t = threadIdx.x;
    const int d = t >> 2, q = t & 3;

    const float* Mrow = cores0 + (size_t)h * (DIM * RANK * RANK) + d * (RANK * RANK) + q * 4;
    float4 M[16];
    #pragma unroll
    for (int r = 0; r < 16; ++r)
        M[r] = *reinterpret_cast<const float4*>(Mrow + r * RANK);

    for (int i = beg; i < beg + cnt; ++i) {
        const int b = list1[i];
        const int h3 = hs[b * 4 + 3];
        const float* ev = end_core + (size_t)h3 * (DIM * RANK) + d * RANK;
        float4 acc = make_float4(0.f, 0.f, 0.f, 0.f);
        #pragma unroll
        for (int p = 0; p < 4; ++p) {
            float4 vv = *reinterpret_cast<const float4*>(ev + p * 4);
            fma4(acc, vv.x, M[4 * p + 0]);
            fma4(acc, vv.y, M[4 * p + 1]);
            fma4(acc, vv.z, M[4 * p + 2]);
            fma4(acc, vv.w, M[4 * p + 3]);
        }
        *reinterpret_cast<float4*>(v1 + (size_t)b * (DIM * RANK) + t * 4) = acc;
    }
}

// pass2: out[b][d] = dot(start_core[h0[b]][d], einsum('drs,dr->ds', cores[1][h2[b]], v1[b]))
__global__ __launch_bounds__(256) void pass2_kernel(const int* __restrict__ hs,
                                                    const float* __restrict__ start_core,
                                                    const float* __restrict__ cores1,
                                                    const int* __restrict__ off2,
                                                    const int* __restrict__ hist2,
                                                    const int* __restrict__ list2,
                                                    const float* __restrict__ v1,
                                                    float* __restrict__ out) {
    const int h = blockIdx.x;
    const int cnt = hist2[h];
    if (cnt == 0) return;
    const int beg = off2[h];
    const int t = threadIdx.x;
    const int d = t >> 2, q = t & 3;

    const float* Mrow = cores1 + (size_t)h * (DIM * RANK * RANK) + d * (RANK * RANK) + q * 4;
    float4 M[16];
    #pragma unroll
    for (int r = 0; r < 16; ++r)
        M[r] = *reinterpret_cast<const float4*>(Mrow + r * RANK);

    for (int i = beg; i < beg + cnt; ++i) {
        const int b = list2[i];
        const int h0 = hs[b * 4 + 0];
        const float* vv_ = v1 + (size_t)b * (DIM * RANK) + d * RANK;
        float4 acc = make_float4(0.f, 0.f, 0.f, 0.f);
        #pragma unroll
        for (int p = 0; p < 4; ++p) {
            float4 vv = *reinterpret_cast<const float4*>(vv_ + p * 4);
            fma4(acc, vv.x, M[4 * p + 0]);
            fma4(acc, vv.y, M[4 * p + 1]);
            fma4(acc, vv.z, M[4 * p + 2]);
            fma4(acc, vv.w, M[4 * p + 3]);
        }
        float4 sc = *reinterpret_cast<const float4*>(
            start_core + (size_t)h0 * (DIM * RANK) + d * RANK + q * 4);
        float partial = acc.x * sc.x + acc.y * sc.y + acc.z * sc.z + acc.w * sc.w;
        partial += __shfl_xor(partial, 1);
        partial += __shfl_xor(partial, 2);
        if (q == 0) out[(size_t)b * DIM + d] = partial;
    }
}

extern "C" void kernel_launch(void* const* d_in, const int* in_sizes, int n_in,
                              void* d_out, int out_size, void* d_ws, size_t ws_size,
                              hipStream_t stream) {
    const int*   hs         = (const int*)d_in[0];
    const float* start_core = (const float*)d_in[1];
    const float* end_core   = (const float*)d_in[2];
    const float* cores      = (const float*)d_in[3];
    float*       out        = (float*)d_out;
    const int B = in_sizes[0] / 4;

    // workspace layout (ints then floats; v1 offset 327680 B, 16B-aligned)
    int* hist1 = (int*)d_ws;
    int* hist2 = hist1 + HRANGE;
    int* off1  = hist2 + HRANGE;
    int* off2  = off1  + HRANGE;
    int* cur1  = off2  + HRANGE;
    int* cur2  = cur1  + HRANGE;
    int* list1 = cur2  + HRANGE;
    int* list2 = list1 + B;
    float* v1  = (float*)(list2 + B);

    zero_hist<<<(2 * HRANGE + 255) / 256, 256, 0, stream>>>(hist1);
    hist_kernel<<<(B + 255) / 256, 256, 0, stream>>>(hs, hist1, hist2, B);
    scan_kernel<<<1, 1024, 0, stream>>>(hist1, hist2, off1, cur1, off2, cur2);
    scatter_kernel<<<(B + 255) / 256, 256, 0, stream>>>(hs, cur1, cur2, list1, list2, B);
    pass1_kernel<<<HRANGE, 256, 0, stream>>>(hs, end_core, cores, off1, hist1, list1, v1);
    pass2_kernel<<<HRANGE, 256, 0, stream>>>(hs, start_core,
                                             cores + (size_t)HRANGE * DIM * RANK * RANK,
                                             off2, hist2, list2, v1, out);
}

// Round 4
// 258.910 us; speedup vs baseline: 2.2124x; 1.0093x over previous
//
#include <hip/hip_runtime.h>

#define HRANGE 8192
#define DIM 64
#define RANK 16
#define MAXB 128   // staged bin-chunk size (bins are Poisson(2); chunk loop handles any cnt)

// ---------------------------------------------------------------------------
// Counting-sort b's by h1 (stage-1) and h2 (stage-2); one block per h-bin
// loads its 64KB core row into registers once and applies it to all b's in
// the bin. R4: bin metadata staged in parallel into LDS + 2-deep software
// pipeline on the per-b gathers (kill the serial list->hs->gather chain).
// ---------------------------------------------------------------------------

__device__ __forceinline__ void fma4(float4& a, float s, const float4& m) {
    a.x = fmaf(s, m.x, a.x); a.y = fmaf(s, m.y, a.y);
    a.z = fmaf(s, m.z, a.z); a.w = fmaf(s, m.w, a.w);
}

__global__ __launch_bounds__(256) void zero_hist(int* hist) {
    int i = blockIdx.x * blockDim.x + threadIdx.x;
    if (i < 2 * HRANGE) hist[i] = 0;
}

__global__ __launch_bounds__(256) void hist_kernel(const int* __restrict__ hs,
                                                   int* hist1, int* hist2, int B) {
    int b = blockIdx.x * blockDim.x + threadIdx.x;
    if (b >= B) return;
    atomicAdd(&hist1[hs[b * 4 + 1]], 1);
    atomicAdd(&hist2[hs[b * 4 + 2]], 1);
}

// single-block exclusive scan of two 8192-bin histograms
__global__ __launch_bounds__(1024) void scan_kernel(const int* __restrict__ hist1,
                                                    const int* __restrict__ hist2,
                                                    int* off1, int* cur1,
                                                    int* off2, int* cur2) {
    __shared__ int part[1024];
    const int t = threadIdx.x;
    for (int which = 0; which < 2; ++which) {
        const int* hist = which ? hist2 : hist1;
        int* off = which ? off2 : off1;
        int* cur = which ? cur2 : cur1;
        int loc[8]; int sum = 0;
        #pragma unroll
        for (int i = 0; i < 8; ++i) { loc[i] = sum; sum += hist[t * 8 + i]; }
        part[t] = sum;
        __syncthreads();
        for (int dstep = 1; dstep < 1024; dstep <<= 1) {
            int v_ = (t >= dstep) ? part[t - dstep] : 0;
            __syncthreads();
            part[t] += v_;
            __syncthreads();
        }
        int base = (t == 0) ? 0 : part[t - 1];
        #pragma unroll
        for (int i = 0; i < 8; ++i) { int o = base + loc[i]; off[t*8+i] = o; cur[t*8+i] = o; }
        __syncthreads();
    }
}

__global__ __launch_bounds__(256) void scatter_kernel(const int* __restrict__ hs,
                                                      int* cur1, int* cur2,
                                                      int* list1, int* list2, int B) {
    int b = blockIdx.x * blockDim.x + threadIdx.x;
    if (b >= B) return;
    int p1 = atomicAdd(&cur1[hs[b * 4 + 1]], 1); list1[p1] = b;
    int p2 = atomicAdd(&cur2[hs[b * 4 + 2]], 1); list2[p2] = b;
}

// pass1: v1[b] = einsum('drs,dr->ds', cores[0][h1[b]], end_core[h3[b]])
__global__ __launch_bounds__(256) void pass1_kernel(const int* __restrict__ hs,
                                                    const float* __restrict__ end_core,
                                                    const float* __restrict__ cores0,
                                                    const int* __restrict__ off1,
                                                    const int* __restrict__ hist1,
                                                    const int* __restrict__ list1,
                                                    float* __restrict__ v1) {
    const int h = blockIdx.x;
    const int cnt = hist1[h];
    if (cnt == 0) return;
    const int beg = off1[h];
    const int t = threadIdx.x;
    const int d = t >> 2, q = t & 3;

    __shared__ int sb[MAXB];
    __shared__ int sh[MAXB];

    const float* Mrow = cores0 + (size_t)h * (DIM * RANK * RANK) + d * (RANK * RANK) + q * 4;
    float4 M[16];
    #pragma unroll
    for (int r = 0; r < 16; ++r)
        M[r] = *reinterpret_cast<const float4*>(Mrow + r * RANK);

    for (int base = 0; base < cnt; base += MAXB) {
        const int n = min(cnt - base, MAXB);
        __syncthreads();                       // WAR on sb/sh across chunks
        for (int i = t; i < n; i += 256) {
            int b = list1[beg + base + i];
            sb[i] = b;
            sh[i] = hs[b * 4 + 3];
        }
        __syncthreads();

        float4 nv[4];
        {
            const float* e0 = end_core + (size_t)sh[0] * (DIM * RANK) + d * RANK;
            nv[0] = *reinterpret_cast<const float4*>(e0 + 0);
            nv[1] = *reinterpret_cast<const float4*>(e0 + 4);
            nv[2] = *reinterpret_cast<const float4*>(e0 + 8);
            nv[3] = *reinterpret_cast<const float4*>(e0 + 12);
        }
        for (int i = 0; i < n; ++i) {
            float4 c0 = nv[0], c1 = nv[1], c2 = nv[2], c3 = nv[3];
            if (i + 1 < n) {                   // prefetch next b's gather
                const float* e = end_core + (size_t)sh[i + 1] * (DIM * RANK) + d * RANK;
                nv[0] = *reinterpret_cast<const float4*>(e + 0);
                nv[1] = *reinterpret_cast<const float4*>(e + 4);
                nv[2] = *reinterpret_cast<const float4*>(e + 8);
                nv[3] = *reinterpret_cast<const float4*>(e + 12);
            }
            float4 acc = make_float4(0.f, 0.f, 0.f, 0.f);
            fma4(acc, c0.x, M[0]);  fma4(acc, c0.y, M[1]);
            fma4(acc, c0.z, M[2]);  fma4(acc, c0.w, M[3]);
            fma4(acc, c1.x, M[4]);  fma4(acc, c1.y, M[5]);
            fma4(acc, c1.z, M[6]);  fma4(acc, c1.w, M[7]);
            fma4(acc, c2.x, M[8]);  fma4(acc, c2.y, M[9]);
            fma4(acc, c2.z, M[10]); fma4(acc, c2.w, M[11]);
            fma4(acc, c3.x, M[12]); fma4(acc, c3.y, M[13]);
            fma4(acc, c3.z, M[14]); fma4(acc, c3.w, M[15]);
            *reinterpret_cast<float4*>(v1 + (size_t)sb[i] * (DIM * RANK) + t * 4) = acc;
        }
    }
}

// pass2: out[b][d] = dot(start_core[h0[b]][d], einsum('drs,dr->ds', cores[1][h2[b]], v1[b]))
__global__ __launch_bounds__(256) void pass2_kernel(const int* __restrict__ hs,
                                                    const float* __restrict__ start_core,
                                                    const float* __restrict__ cores1,
                                                    const int* __restrict__ off2,
                                                    const int* __restrict__ hist2,
                                                    const int* __restrict__ list2,
                                                    const float* __restrict__ v1,
                                                    float* __restrict__ out) {
    const int h = blockIdx.x;
    const int cnt = hist2[h];
    if (cnt == 0) return;
    const int beg = off2[h];
    const int t = threadIdx.x;
    const int d = t >> 2, q = t & 3;

    __shared__ int sb[MAXB];
    __shared__ int sh0[MAXB];

    const float* Mrow = cores1 + (size_t)h * (DIM * RANK * RANK) + d * (RANK * RANK) + q * 4;
    float4 M[16];
    #pragma unroll
    for (int r = 0; r < 16; ++r)
        M[r] = *reinterpret_cast<const float4*>(Mrow + r * RANK);

    for (int base = 0; base < cnt; base += MAXB) {
        const int n = min(cnt - base, MAXB);
        __syncthreads();
        for (int i = t; i < n; i += 256) {
            int b = list2[beg + base + i];
            sb[i] = b;
            sh0[i] = hs[b * 4 + 0];
        }
        __syncthreads();

        float4 nv[4]; float4 nsc;
        {
            const float* v0 = v1 + (size_t)sb[0] * (DIM * RANK) + d * RANK;
            nv[0] = *reinterpret_cast<const float4*>(v0 + 0);
            nv[1] = *reinterpret_cast<const float4*>(v0 + 4);
            nv[2] = *reinterpret_cast<const float4*>(v0 + 8);
            nv[3] = *reinterpret_cast<const float4*>(v0 + 12);
            nsc = *reinterpret_cast<const float4*>(
                start_core + (size_t)sh0[0] * (DIM * RANK) + d * RANK + q * 4);
        }
        for (int i = 0; i < n; ++i) {
            float4 c0 = nv[0], c1 = nv[1], c2 = nv[2], c3 = nv[3];
            float4 sc = nsc;
            if (i + 1 < n) {
                const float* vv_ = v1 + (size_t)sb[i + 1] * (DIM * RANK) + d * RANK;
                nv[0] = *reinterpret_cast<const float4*>(vv_ + 0);
                nv[1] = *reinterpret_cast<const float4*>(vv_ + 4);
                nv[2] = *reinterpret_cast<const float4*>(vv_ + 8);
                nv[3] = *reinterpret_cast<const float4*>(vv_ + 12);
                nsc = *reinterpret_cast<const float4*>(
                    start_core + (size_t)sh0[i + 1] * (DIM * RANK) + d * RANK + q * 4);
            }
            float4 acc = make_float4(0.f, 0.f, 0.f, 0.f);
            fma4(acc, c0.x, M[0]);  fma4(acc, c0.y, M[1]);
            fma4(acc, c0.z, M[2]);  fma4(acc, c0.w, M[3]);
            fma4(acc, c1.x, M[4]);  fma4(acc, c1.y, M[5]);
            fma4(acc, c1.z, M[6]);  fma4(acc, c1.w, M[7]);
            fma4(acc, c2.x, M[8]);  fma4(acc, c2.y, M[9]);
            fma4(acc, c2.z, M[10]); fma4(acc, c2.w, M[11]);
            fma4(acc, c3.x, M[12]); fma4(acc, c3.y, M[13]);
            fma4(acc, c3.z, M[14]); fma4(acc, c3.w, M[15]);
            float partial = acc.x * sc.x + acc.y * sc.y + acc.z * sc.z + acc.w * sc.w;
            partial += __shfl_xor(partial, 1);
            partial += __shfl_xor(partial, 2);
            if (q == 0) out[(size_t)sb[i] * DIM + d] = partial;
        }
    }
}

extern "C" void kernel_launch(void* const* d_in, const int* in_sizes, int n_in,
                              void* d_out, int out_size, void* d_ws, size_t ws_size,
                              hipStream_t stream) {
    const int*   hs         = (const int*)d_in[0];
    const float* start_core = (const float*)d_in[1];
    const float* end_core   = (const float*)d_in[2];
    const float* cores      = (const float*)d_in[3];
    float*       out        = (float*)d_out;
    const int B = in_sizes[0] / 4;

    int* hist1 = (int*)d_ws;
    int* hist2 = hist1 + HRANGE;
    int* off1  = hist2 + HRANGE;
    int* off2  = off1  + HRANGE;
    int* cur1  = off2  + HRANGE;
    int* cur2  = cur1  + HRANGE;
    int* list1 = cur2  + HRANGE;
    int* list2 = list1 + B;
    float* v1  = (float*)(list2 + B);

    zero_hist<<<(2 * HRANGE + 255) / 256, 256, 0, stream>>>(hist1);
    hist_kernel<<<(B + 255) / 256, 256, 0, stream>>>(hs, hist1, hist2, B);
    scan_kernel<<<1, 1024, 0, stream>>>(hist1, hist2, off1, cur1, off2, cur2);
    scatter_kernel<<<(B + 255) / 256, 256, 0, stream>>>(hs, cur1, cur2, list1, list2, B);
    pass1_kernel<<<HRANGE, 256, 0, stream>>>(hs, end_core, cores, off1, hist1, list1, v1);
    pass2_kernel<<<HRANGE, 256, 0, stream>>>(hs, start_core,
                                             cores + (size_t)HRANGE * DIM * RANK * RANK,
                                             off2, hist2, list2, v1, out);
}

// Round 5
// 230.448 us; speedup vs baseline: 2.4857x; 1.1235x over previous
//
#include <hip/hip_runtime.h>

#define HRANGE 8192
#define DIM 64
#define RANK 16
#define CAP 64

// ---------------------------------------------------------------------------
// R5: counting-sort WITHOUT scan (fixed-capacity bins + overflow list), and
// one-wave (64-thread) pass blocks, one per (h, d-quarter): ~16 independent
// 16KB row-streams per CU. Kernels: zero, bin, pass1, pass2.
// ---------------------------------------------------------------------------

__device__ __forceinline__ void fma4(float4& a, float s, const float4& m) {
    a.x = fmaf(s, m.x, a.x); a.y = fmaf(s, m.y, a.y);
    a.z = fmaf(s, m.z, a.z); a.w = fmaf(s, m.w, a.w);
}
__device__ __forceinline__ float4 ld4(const float* p) {
    return *reinterpret_cast<const float4*>(p);
}

__global__ __launch_bounds__(256) void zero_kernel(int* p, int n) {
    int i = blockIdx.x * blockDim.x + threadIdx.x;
    if (i < n) p[i] = 0;
}

__global__ __launch_bounds__(256) void bin_kernel(const int* __restrict__ hs,
                                                  int* hist1, int* hist2, int* ovfc,
                                                  int* list1, int* list2,
                                                  int* ovf1, int* ovf2, int B) {
    int b = blockIdx.x * blockDim.x + threadIdx.x;
    if (b >= B) return;
    int h1 = hs[b * 4 + 1];
    int s1 = atomicAdd(&hist1[h1], 1);
    if (s1 < CAP) list1[h1 * CAP + s1] = b;
    else { int o = atomicAdd(&ovfc[0], 1); ovf1[o] = b; }
    int h2 = hs[b * 4 + 2];
    int s2 = atomicAdd(&hist2[h2], 1);
    if (s2 < CAP) list2[h2 * CAP + s2] = b;
    else { int o = atomicAdd(&ovfc[1], 1); ovf2[o] = b; }
}

// pass1: v1[b][d][s] = sum_r cores0[h1[b]][d][r][s] * end_core[h3[b]][d][r]
// block = (h, d-quarter), 64 threads = 16 d x 4 s-quads. Tail blocks: overflow.
__global__ __launch_bounds__(64) void pass1_kernel(const int* __restrict__ hs,
                                                   const float* __restrict__ end_core,
                                                   const float* __restrict__ cores0,
                                                   const int* __restrict__ hist1,
                                                   const int* __restrict__ list1,
                                                   const int* __restrict__ ovfc,
                                                   const int* __restrict__ ovf1,
                                                   float* __restrict__ v1) {
    const int lane = threadIdx.x;
    const int dl = lane >> 2, q = lane & 3;
    const int bid = blockIdx.x;

    if (bid < HRANGE * 4) {
        const int h = bid >> 2;
        const int cnt = hist1[h];
        if (cnt == 0) return;
        const int n = cnt < CAP ? cnt : CAP;
        const int d = (bid & 3) * 16 + dl;

        const float* Mrow = cores0 + ((size_t)h * DIM + d) * (RANK * RANK) + q * 4;
        float4 M[16];
        #pragma unroll
        for (int r = 0; r < 16; ++r) M[r] = ld4(Mrow + r * RANK);

        __shared__ int sb[CAP], sh[CAP];
        if (lane < n) {
            int b = list1[h * CAP + lane];
            sb[lane] = b;
            sh[lane] = hs[b * 4 + 3];
        }
        __syncthreads();

        float4 n0, n1, n2, n3;
        { const float* e = end_core + ((size_t)sh[0] * DIM + d) * RANK;
          n0 = ld4(e); n1 = ld4(e + 4); n2 = ld4(e + 8); n3 = ld4(e + 12); }
        for (int i = 0; i < n; ++i) {
            float4 c0 = n0, c1 = n1, c2 = n2, c3 = n3;
            if (i + 1 < n) {
                const float* e = end_core + ((size_t)sh[i + 1] * DIM + d) * RANK;
                n0 = ld4(e); n1 = ld4(e + 4); n2 = ld4(e + 8); n3 = ld4(e + 12);
            }
            float4 acc = make_float4(0.f, 0.f, 0.f, 0.f);
            fma4(acc, c0.x, M[0]);  fma4(acc, c0.y, M[1]);
            fma4(acc, c0.z, M[2]);  fma4(acc, c0.w, M[3]);
            fma4(acc, c1.x, M[4]);  fma4(acc, c1.y, M[5]);
            fma4(acc, c1.z, M[6]);  fma4(acc, c1.w, M[7]);
            fma4(acc, c2.x, M[8]);  fma4(acc, c2.y, M[9]);
            fma4(acc, c2.z, M[10]); fma4(acc, c2.w, M[11]);
            fma4(acc, c3.x, M[12]); fma4(acc, c3.y, M[13]);
            fma4(acc, c3.z, M[14]); fma4(acc, c3.w, M[15]);
            *reinterpret_cast<float4*>(
                v1 + (size_t)sb[i] * (DIM * RANK) + d * RANK + q * 4) = acc;
        }
    } else {
        // overflow entries (expected 0): direct per-b computation
        const int d = (bid - HRANGE * 4) * 16 + dl;
        const int no = ovfc[0];
        for (int i = 0; i < no; ++i) {
            int b = ovf1[i];
            int h = hs[b * 4 + 1], h3 = hs[b * 4 + 3];
            const float* Mrow = cores0 + ((size_t)h * DIM + d) * (RANK * RANK) + q * 4;
            const float* e = end_core + ((size_t)h3 * DIM + d) * RANK;
            float4 e0 = ld4(e), e1 = ld4(e + 4), e2 = ld4(e + 8), e3 = ld4(e + 12);
            const float ev[16] = {e0.x, e0.y, e0.z, e0.w, e1.x, e1.y, e1.z, e1.w,
                                  e2.x, e2.y, e2.z, e2.w, e3.x, e3.y, e3.z, e3.w};
            float4 acc = make_float4(0.f, 0.f, 0.f, 0.f);
            #pragma unroll
            for (int r = 0; r < 16; ++r) fma4(acc, ev[r], ld4(Mrow + r * RANK));
            *reinterpret_cast<float4*>(
                v1 + (size_t)b * (DIM * RANK) + d * RANK + q * 4) = acc;
        }
    }
}

// pass2: out[b][d] = dot(start_core[h0[b]][d], sum_r cores1[h2[b]][d][r][:] * v1[b][d][r])
__global__ __launch_bounds__(64) void pass2_kernel(const int* __restrict__ hs,
                                                   const float* __restrict__ start_core,
                                                   const float* __restrict__ cores1,
                                                   const int* __restrict__ hist2,
                                                   const int* __restrict__ list2,
                                                   const int* __restrict__ ovfc,
                                                   const int* __restrict__ ovf2,
                                                   const float* __restrict__ v1,
                                                   float* __restrict__ out) {
    const int lane = threadIdx.x;
    const int dl = lane >> 2, q = lane & 3;
    const int bid = blockIdx.x;

    if (bid < HRANGE * 4) {
        const int h = bid >> 2;
        const int cnt = hist2[h];
        if (cnt == 0) return;
        const int n = cnt < CAP ? cnt : CAP;
        const int d = (bid & 3) * 16 + dl;

        const float* Mrow = cores1 + ((size_t)h * DIM + d) * (RANK * RANK) + q * 4;
        float4 M[16];
        #pragma unroll
        for (int r = 0; r < 16; ++r) M[r] = ld4(Mrow + r * RANK);

        __shared__ int sb[CAP], sh0[CAP];
        if (lane < n) {
            int b = list2[h * CAP + lane];
            sb[lane] = b;
            sh0[lane] = hs[b * 4 + 0];
        }
        __syncthreads();

        float4 n0, n1, n2, n3, nsc;
        { const float* vv = v1 + (size_t)sb[0] * (DIM * RANK) + d * RANK;
          n0 = ld4(vv); n1 = ld4(vv + 4); n2 = ld4(vv + 8); n3 = ld4(vv + 12);
          nsc = ld4(start_core + ((size_t)sh0[0] * DIM + d) * RANK + q * 4); }
        for (int i = 0; i < n; ++i) {
            float4 c0 = n0, c1 = n1, c2 = n2, c3 = n3, sc = nsc;
            if (i + 1 < n) {
                const float* vv = v1 + (size_t)sb[i + 1] * (DIM * RANK) + d * RANK;
                n0 = ld4(vv); n1 = ld4(vv + 4); n2 = ld4(vv + 8); n3 = ld4(vv + 12);
                nsc = ld4(start_core + ((size_t)sh0[i + 1] * DIM + d) * RANK + q * 4);
            }
            float4 acc = make_float4(0.f, 0.f, 0.f, 0.f);
            fma4(acc, c0.x, M[0]);  fma4(acc, c0.y, M[1]);
            fma4(acc, c0.z, M[2]);  fma4(acc, c0.w, M[3]);
            fma4(acc, c1.x, M[4]);  fma4(acc, c1.y, M[5]);
            fma4(acc, c1.z, M[6]);  fma4(acc, c1.w, M[7]);
            fma4(acc, c2.x, M[8]);  fma4(acc, c2.y, M[9]);
            fma4(acc, c2.z, M[10]); fma4(acc, c2.w, M[11]);
            fma4(acc, c3.x, M[12]); fma4(acc, c3.y, M[13]);
            fma4(acc, c3.z, M[14]); fma4(acc, c3.w, M[15]);
            float partial = acc.x * sc.x + acc.y * sc.y + acc.z * sc.z + acc.w * sc.w;
            partial += __shfl_xor(partial, 1);
            partial += __shfl_xor(partial, 2);
            if (q == 0) out[(size_t)sb[i] * DIM + d] = partial;
        }
    } else {
        const int d = (bid - HRANGE * 4) * 16 + dl;
        const int no = ovfc[0];
        for (int i = 0; i < no; ++i) {
            int b = ovf2[i];
            int h = hs[b * 4 + 2], h0 = hs[b * 4 + 0];
            const float* Mrow = cores1 + ((size_t)h * DIM + d) * (RANK * RANK) + q * 4;
            const float* vv = v1 + (size_t)b * (DIM * RANK) + d * RANK;
            float4 e0 = ld4(vv), e1 = ld4(vv + 4), e2 = ld4(vv + 8), e3 = ld4(vv + 12);
            const float ev[16] = {e0.x, e0.y, e0.z, e0.w, e1.x, e1.y, e1.z, e1.w,
                                  e2.x, e2.y, e2.z, e2.w, e3.x, e3.y, e3.z, e3.w};
            float4 acc = make_float4(0.f, 0.f, 0.f, 0.f);
            #pragma unroll
            for (int r = 0; r < 16; ++r) fma4(acc, ev[r], ld4(Mrow + r * RANK));
            float4 sc = ld4(start_core + ((size_t)h0 * DIM + d) * RANK + q * 4);
            float partial = acc.x * sc.x + acc.y * sc.y + acc.z * sc.z + acc.w * sc.w;
            partial += __shfl_xor(partial, 1);
            partial += __shfl_xor(partial, 2);
            if (q == 0) out[(size_t)b * DIM + d] = partial;
        }
    }
}

extern "C" void kernel_launch(void* const* d_in, const int* in_sizes, int n_in,
                              void* d_out, int out_size, void* d_ws, size_t ws_size,
                              hipStream_t stream) {
    const int*   hs         = (const int*)d_in[0];
    const float* start_core = (const float*)d_in[1];
    const float* end_core   = (const float*)d_in[2];
    const float* cores      = (const float*)d_in[3];
    float*       out        = (float*)d_out;
    const int B = in_sizes[0] / 4;

    // workspace: v1 first (16B-aligned), then int arrays
    float* v1  = (float*)d_ws;                       // B*DIM*RANK floats (64 MB)
    int* hist1 = (int*)(v1 + (size_t)B * DIM * RANK);
    int* hist2 = hist1 + HRANGE;
    int* ovfc  = hist2 + HRANGE;                     // 2 counters
    int* list1 = ovfc + 2;
    int* list2 = list1 + HRANGE * CAP;
    int* ovf1  = list2 + HRANGE * CAP;
    int* ovf2  = ovf1 + B;

    zero_kernel<<<(2 * HRANGE + 2 + 255) / 256, 256, 0, stream>>>(hist1, 2 * HRANGE + 2);
    bin_kernel<<<(B + 255) / 256, 256, 0, stream>>>(hs, hist1, hist2, ovfc,
                                                    list1, list2, ovf1, ovf2, B);
    pass1_kernel<<<HRANGE * 4 + 4, 64, 0, stream>>>(hs, end_core, cores,
                                                    hist1, list1, ovfc, ovf1, v1);
    pass2_kernel<<<HRANGE * 4 + 4, 64, 0, stream>>>(hs, start_core,
                                                    cores + (size_t)HRANGE * DIM * RANK * RANK,
                                                    hist2, list2, ovfc + 1, ovf2, v1, out);
}

// Round 7
// 230.303 us; speedup vs baseline: 2.4872x; 1.0006x over previous
//
#include <hip/hip_runtime.h>

#define HRANGE 8192
#define DIM 64
#define RANK 16
#define CAP 64

// ---------------------------------------------------------------------------
// R7 (= R6 with compile fix): counting-sort (no scan) + nonempty-bin worklist;
// one-wave pass blocks, one per (worklist entry, d-quarter). Core rows loaded
// via nontemporal float4 (read-once -> don't pollute L2/L3). v1 intermediate
// stored as bf16 (32 MB, L3-resident between passes).
// ---------------------------------------------------------------------------

typedef float floatx4 __attribute__((ext_vector_type(4)));

__device__ __forceinline__ void fma4(float4& a, float s, const float4& m) {
    a.x = fmaf(s, m.x, a.x); a.y = fmaf(s, m.y, a.y);
    a.z = fmaf(s, m.z, a.z); a.w = fmaf(s, m.w, a.w);
}
__device__ __forceinline__ float4 ld4(const float* p) {
    return *reinterpret_cast<const float4*>(p);
}
__device__ __forceinline__ float4 ldnt4(const float* p) {
    floatx4 t = __builtin_nontemporal_load(reinterpret_cast<const floatx4*>(p));
    return make_float4(t.x, t.y, t.z, t.w);
}
__device__ __forceinline__ unsigned short f2bf(float x) {
    unsigned int u = __float_as_uint(x);
    u += 0x7FFFu + ((u >> 16) & 1u);          // RNE
    return (unsigned short)(u >> 16);
}
__device__ __forceinline__ float blo(unsigned int u) { return __uint_as_float(u << 16); }
__device__ __forceinline__ float bhi(unsigned int u) { return __uint_as_float(u & 0xFFFF0000u); }

__global__ __launch_bounds__(256) void zero_kernel(int* p, int n) {
    int i = blockIdx.x * blockDim.x + threadIdx.x;
    if (i < n) p[i] = 0;
}

// hist + fixed-cap lists + overflow + nonempty worklists, one kernel
__global__ __launch_bounds__(256) void bin_kernel(const int* __restrict__ hs,
                                                  int* hist1, int* hist2,
                                                  int* ovfc, int* nec,
                                                  int* wl1, int* wl2,
                                                  int* list1, int* list2,
                                                  int* ovf1, int* ovf2, int B) {
    int b = blockIdx.x * blockDim.x + threadIdx.x;
    if (b >= B) return;
    int h1 = hs[b * 4 + 1];
    int s1 = atomicAdd(&hist1[h1], 1);
    if (s1 == 0) { int w = atomicAdd(&nec[0], 1); wl1[w] = h1; }
    if (s1 < CAP) list1[h1 * CAP + s1] = b;
    else { int o = atomicAdd(&ovfc[0], 1); ovf1[o] = b; }
    int h2 = hs[b * 4 + 2];
    int s2 = atomicAdd(&hist2[h2], 1);
    if (s2 == 0) { int w = atomicAdd(&nec[1], 1); wl2[w] = h2; }
    if (s2 < CAP) list2[h2 * CAP + s2] = b;
    else { int o = atomicAdd(&ovfc[1], 1); ovf2[o] = b; }
}

// pass1: v1[b][d][s] = sum_r cores0[h1[b]][d][r][s] * end_core[h3[b]][d][r]
// block = (worklist idx, d-quarter); 64 threads = 16 d x 4 s-quads.
__global__ __launch_bounds__(64) void pass1_kernel(const int* __restrict__ hs,
                                                   const float* __restrict__ end_core,
                                                   const float* __restrict__ cores0,
                                                   const int* __restrict__ hist1,
                                                   const int* __restrict__ list1,
                                                   const int* __restrict__ nec,
                                                   const int* __restrict__ wl1,
                                                   const int* __restrict__ ovfc,
                                                   const int* __restrict__ ovf1,
                                                   unsigned short* __restrict__ v1) {
    const int lane = threadIdx.x;
    const int dl = lane >> 2, q = lane & 3;
    const int bid = blockIdx.x;

    if (bid < HRANGE * 4) {
        const int widx = bid >> 2;
        if (widx >= nec[0]) return;
        const int h = wl1[widx];
        const int d = (bid & 3) * 16 + dl;

        const float* Mrow = cores0 + ((size_t)h * DIM + d) * (RANK * RANK) + q * 4;
        float4 M[16];
        #pragma unroll
        for (int r = 0; r < 16; ++r) M[r] = ldnt4(Mrow + r * RANK);

        const int cnt = hist1[h];
        const int n = cnt < CAP ? cnt : CAP;

        __shared__ int sb[CAP], sh[CAP];
        if (lane < n) {
            int b = list1[h * CAP + lane];
            sb[lane] = b;
            sh[lane] = hs[b * 4 + 3];
        }
        __syncthreads();

        float4 n0, n1, n2, n3;
        { const float* e = end_core + ((size_t)sh[0] * DIM + d) * RANK;
          n0 = ld4(e); n1 = ld4(e + 4); n2 = ld4(e + 8); n3 = ld4(e + 12); }
        for (int i = 0; i < n; ++i) {
            float4 c0 = n0, c1 = n1, c2 = n2, c3 = n3;
            if (i + 1 < n) {
                const float* e = end_core + ((size_t)sh[i + 1] * DIM + d) * RANK;
                n0 = ld4(e); n1 = ld4(e + 4); n2 = ld4(e + 8); n3 = ld4(e + 12);
            }
            float4 acc = make_float4(0.f, 0.f, 0.f, 0.f);
            fma4(acc, c0.x, M[0]);  fma4(acc, c0.y, M[1]);
            fma4(acc, c0.z, M[2]);  fma4(acc, c0.w, M[3]);
            fma4(acc, c1.x, M[4]);  fma4(acc, c1.y, M[5]);
            fma4(acc, c1.z, M[6]);  fma4(acc, c1.w, M[7]);
            fma4(acc, c2.x, M[8]);  fma4(acc, c2.y, M[9]);
            fma4(acc, c2.z, M[10]); fma4(acc, c2.w, M[11]);
            fma4(acc, c3.x, M[12]); fma4(acc, c3.y, M[13]);
            fma4(acc, c3.z, M[14]); fma4(acc, c3.w, M[15]);
            *reinterpret_cast<ushort4*>(v1 + (size_t)sb[i] * (DIM * RANK) + d * RANK + q * 4) =
                make_ushort4(f2bf(acc.x), f2bf(acc.y), f2bf(acc.z), f2bf(acc.w));
        }
    } else {
        // overflow entries (expected ~0)
        const int d = (bid - HRANGE * 4) * 16 + dl;
        const int no = ovfc[0];
        for (int i = 0; i < no; ++i) {
            int b = ovf1[i];
            int h = hs[b * 4 + 1], h3 = hs[b * 4 + 3];
            const float* Mrow = cores0 + ((size_t)h * DIM + d) * (RANK * RANK) + q * 4;
            const float* e = end_core + ((size_t)h3 * DIM + d) * RANK;
            float4 e0 = ld4(e), e1 = ld4(e + 4), e2 = ld4(e + 8), e3 = ld4(e + 12);
            const float ev[16] = {e0.x, e0.y, e0.z, e0.w, e1.x, e1.y, e1.z, e1.w,
                                  e2.x, e2.y, e2.z, e2.w, e3.x, e3.y, e3.z, e3.w};
            float4 acc = make_float4(0.f, 0.f, 0.f, 0.f);
            #pragma unroll
            for (int r = 0; r < 16; ++r) fma4(acc, ev[r], ld4(Mrow + r * RANK));
            *reinterpret_cast<ushort4*>(v1 + (size_t)b * (DIM * RANK) + d * RANK + q * 4) =
                make_ushort4(f2bf(acc.x), f2bf(acc.y), f2bf(acc.z), f2bf(acc.w));
        }
    }
}

// pass2: out[b][d] = dot(start_core[h0[b]][d], sum_r cores1[h2[b]][d][r][:] * v1[b][d][r])
__global__ __launch_bounds__(64) void pass2_kernel(const int* __restrict__ hs,
                                                   const float* __restrict__ start_core,
                                                   const float* __restrict__ cores1,
                                                   const int* __restrict__ hist2,
                                                   const int* __restrict__ list2,
                                                   const int* __restrict__ nec,
                                                   const int* __restrict__ wl2,
                                                   const int* __restrict__ ovfc,
                                                   const int* __restrict__ ovf2,
                                                   const unsigned short* __restrict__ v1,
                                                   float* __restrict__ out) {
    const int lane = threadIdx.x;
    const int dl = lane >> 2, q = lane & 3;
    const int bid = blockIdx.x;

    if (bid < HRANGE * 4) {
        const int widx = bid >> 2;
        if (widx >= nec[0]) return;
        const int h = wl2[widx];
        const int d = (bid & 3) * 16 + dl;

        const float* Mrow = cores1 + ((size_t)h * DIM + d) * (RANK * RANK) + q * 4;
        float4 M[16];
        #pragma unroll
        for (int r = 0; r < 16; ++r) M[r] = ldnt4(Mrow + r * RANK);

        const int cnt = hist2[h];
        const int n = cnt < CAP ? cnt : CAP;

        __shared__ int sb[CAP], sh0[CAP];
        if (lane < n) {
            int b = list2[h * CAP + lane];
            sb[lane] = b;
            sh0[lane] = hs[b * 4 + 0];
        }
        __syncthreads();

        uint4 na, nb; float4 nsc;
        { const unsigned short* vv = v1 + (size_t)sb[0] * (DIM * RANK) + d * RANK;
          na = *reinterpret_cast<const uint4*>(vv);
          nb = *reinterpret_cast<const uint4*>(vv + 8);
          nsc = ld4(start_core + ((size_t)sh0[0] * DIM + d) * RANK + q * 4); }
        for (int i = 0; i < n; ++i) {
            uint4 a = na, bb = nb; float4 sc = nsc;
            if (i + 1 < n) {
                const unsigned short* vv = v1 + (size_t)sb[i + 1] * (DIM * RANK) + d * RANK;
                na = *reinterpret_cast<const uint4*>(vv);
                nb = *reinterpret_cast<const uint4*>(vv + 8);
                nsc = ld4(start_core + ((size_t)sh0[i + 1] * DIM + d) * RANK + q * 4);
            }
            float4 c0 = make_float4(blo(a.x),  bhi(a.x),  blo(a.y),  bhi(a.y));
            float4 c1 = make_float4(blo(a.z),  bhi(a.z),  blo(a.w),  bhi(a.w));
            float4 c2 = make_float4(blo(bb.x), bhi(bb.x), blo(bb.y), bhi(bb.y));
            float4 c3 = make_float4(blo(bb.z), bhi(bb.z), blo(bb.w), bhi(bb.w));
            float4 acc = make_float4(0.f, 0.f, 0.f, 0.f);
            fma4(acc, c0.x, M[0]);  fma4(acc, c0.y, M[1]);
            fma4(acc, c0.z, M[2]);  fma4(acc, c0.w, M[3]);
            fma4(acc, c1.x, M[4]);  fma4(acc, c1.y, M[5]);
            fma4(acc, c1.z, M[6]);  fma4(acc, c1.w, M[7]);
            fma4(acc, c2.x, M[8]);  fma4(acc, c2.y, M[9]);
            fma4(acc, c2.z, M[10]); fma4(acc, c2.w, M[11]);
            fma4(acc, c3.x, M[12]); fma4(acc, c3.y, M[13]);
            fma4(acc, c3.z, M[14]); fma4(acc, c3.w, M[15]);
            float partial = acc.x * sc.x + acc.y * sc.y + acc.z * sc.z + acc.w * sc.w;
            partial += __shfl_xor(partial, 1);
            partial += __shfl_xor(partial, 2);
            if (q == 0) out[(size_t)sb[i] * DIM + d] = partial;
        }
    } else {
        const int d = (bid - HRANGE * 4) * 16 + dl;
        const int no = ovfc[0];
        for (int i = 0; i < no; ++i) {
            int b = ovf2[i];
            int h = hs[b * 4 + 2], h0 = hs[b * 4 + 0];
            const float* Mrow = cores1 + ((size_t)h * DIM + d) * (RANK * RANK) + q * 4;
            const unsigned short* vv = v1 + (size_t)b * (DIM * RANK) + d * RANK;
            uint4 a = *reinterpret_cast<const uint4*>(vv);
            uint4 bb = *reinterpret_cast<const uint4*>(vv + 8);
            const float ev[16] = {blo(a.x),  bhi(a.x),  blo(a.y),  bhi(a.y),
                                  blo(a.z),  bhi(a.z),  blo(a.w),  bhi(a.w),
                                  blo(bb.x), bhi(bb.x), blo(bb.y), bhi(bb.y),
                                  blo(bb.z), bhi(bb.z), blo(bb.w), bhi(bb.w)};
            float4 acc = make_float4(0.f, 0.f, 0.f, 0.f);
            #pragma unroll
            for (int r = 0; r < 16; ++r) fma4(acc, ev[r], ld4(Mrow + r * RANK));
            float4 sc = ld4(start_core + ((size_t)h0 * DIM + d) * RANK + q * 4);
            float partial = acc.x * sc.x + acc.y * sc.y + acc.z * sc.z + acc.w * sc.w;
            partial += __shfl_xor(partial, 1);
            partial += __shfl_xor(partial, 2);
            if (q == 0) out[(size_t)b * DIM + d] = partial;
        }
    }
}

extern "C" void kernel_launch(void* const* d_in, const int* in_sizes, int n_in,
                              void* d_out, int out_size, void* d_ws, size_t ws_size,
                              hipStream_t stream) {
    const int*   hs         = (const int*)d_in[0];
    const float* start_core = (const float*)d_in[1];
    const float* end_core   = (const float*)d_in[2];
    const float* cores      = (const float*)d_in[3];
    float*       out        = (float*)d_out;
    const int B = in_sizes[0] / 4;

    // workspace: v1 (bf16, 32 MB, 16B-aligned) then int arrays
    unsigned short* v1 = (unsigned short*)d_ws;       // B*DIM*RANK ushorts
    int* hist1 = (int*)(v1 + (size_t)B * DIM * RANK);
    int* hist2 = hist1 + HRANGE;
    int* ovfc  = hist2 + HRANGE;                      // 2
    int* nec   = ovfc + 2;                            // 2
    int* wl1   = nec + 2;
    int* wl2   = wl1 + HRANGE;
    int* list1 = wl2 + HRANGE;
    int* list2 = list1 + HRANGE * CAP;
    int* ovf1  = list2 + HRANGE * CAP;
    int* ovf2  = ovf1 + B;

    zero_kernel<<<(2 * HRANGE + 4 + 255) / 256, 256, 0, stream>>>(hist1, 2 * HRANGE + 4);
    bin_kernel<<<(B + 255) / 256, 256, 0, stream>>>(hs, hist1, hist2, ovfc, nec,
                                                    wl1, wl2, list1, list2, ovf1, ovf2, B);
    pass1_kernel<<<HRANGE * 4 + 4, 64, 0, stream>>>(hs, end_core, cores,
                                                    hist1, list1, nec, wl1, ovfc, ovf1, v1);
    pass2_kernel<<<HRANGE * 4 + 4, 64, 0, stream>>>(hs, start_core,
                                                    cores + (size_t)HRANGE * DIM * RANK * RANK,
                                                    hist2, list2, nec + 1, wl2, ovfc + 1, ovf2,
                                                    v1, out);
}